// Round 2
// baseline (25.792 us; speedup 1.0000x reference)
//
#include <hip/hip_runtime.h>
#include <hip/hip_bf16.h>

// Embedding gather: out[t, :] = weight[tokens[t], :]
// tokens: [16384] int, weight: [32000, 1024] fp32, out: [16384, 1024] fp32.
//
// v2: 8 tokens per 256-thread block. Each lane moves one float4 per row
// (256 lanes * 16 B = 4096 B = one full row). All 8 gather loads are issued
// back-to-back into separate registers before any store, giving 8 outstanding
// VMEM ops per thread (v1 had 1 -> latency-bound). 2048 blocks * 4 waves =
// 8192 waves = exactly full residency (256 CU * 32 waves).

#define DIM 1024
#define V4  (DIM / 4)        // 256 float4 per row
#define TPB 8                // tokens per block

__global__ __launch_bounds__(256) void embed_gather_kernel(
    const int* __restrict__ tokens,
    const float4* __restrict__ weight,   // [VOCAB][V4]
    float4* __restrict__ out,            // [NTOK][V4]
    int ntok)
{
    int base = blockIdx.x * TPB;
    int lane = threadIdx.x;

    int toks[TPB];
#pragma unroll
    for (int i = 0; i < TPB; ++i) {
        int t = base + i;
        toks[i] = (t < ntok) ? tokens[t] : 0;   // uniform (scalar) loads
    }

    float4 v[TPB];
#pragma unroll
    for (int i = 0; i < TPB; ++i) {
        v[i] = weight[(size_t)toks[i] * V4 + lane];   // 8 independent loads
    }

#pragma unroll
    for (int i = 0; i < TPB; ++i) {
        int t = base + i;
        if (t < ntok)
            out[(size_t)t * V4 + lane] = v[i];        // 8 independent stores
    }
}

extern "C" void kernel_launch(void* const* d_in, const int* in_sizes, int n_in,
                              void* d_out, int out_size, void* d_ws, size_t ws_size,
                              hipStream_t stream) {
    const int*   tokens = (const int*)d_in[0];
    const float* weight = (const float*)d_in[1];
    float*       out    = (float*)d_out;

    int ntok = in_sizes[0];   // 8 * 2048 = 16384

    int nblk = (ntok + TPB - 1) / TPB;   // 2048
    embed_gather_kernel<<<dim3(nblk), dim3(256), 0, stream>>>(
        tokens, (const float4*)weight, (float4*)out, ntok);
}